// Round 11
// baseline (143.971 us; speedup 1.0000x reference)
//
#include <hip/hip_runtime.h>
#include <hip/hip_fp16.h>

// ---------------- bicubic helpers (A = -0.75, torch) ----------------
__device__ __forceinline__ float cc1(float x) {
    return (1.25f * x - 2.25f) * x * x + 1.0f;
}
__device__ __forceinline__ float cc2(float x) {
    return ((-0.75f * x + 3.75f) * x - 6.0f) * x + 3.0f;
}

__device__ __forceinline__ void axis64(int o, float w[4], int idx[4]) {
    float src = (float)o * 63.0f / 255.0f;
    float f = floorf(src);
    float t = src - f;
    w[0] = cc2(t + 1.0f);
    w[1] = cc1(t);
    w[2] = cc1(1.0f - t);
    w[3] = cc2(2.0f - t);
    int i0 = (int)f;
#pragma unroll
    for (int k = 0; k < 4; ++k) idx[k] = min(max(i0 - 1 + k, 0), 63);
}

// Warped absolute sample coordinate (x,y) in the padded [0,306) domain for
// output pixel (i,j), batch b. Pure per-pixel function of flow.
__device__ __forceinline__ float2 warp_coord(const float* __restrict__ flow,
                                             int b, int i, int j) {
    float wwy[4], wwx[4];
    int yi4[4], xi4[4];
    axis64(i, wwy, yi4);
    axis64(j, wwx, xi4);

    const float* fb = flow + (long)b * 2 * 4096;
    float fx = 0.f, fy = 0.f;
#pragma unroll
    for (int m = 0; m < 4; ++m) {
        const float* r0 = fb + yi4[m] * 64;
        float sx = 0.f, sy = 0.f;
#pragma unroll
        for (int n = 0; n < 4; ++n) {
            sx += wwx[n] * r0[xi4[n]];
            sy += wwx[n] * r0[4096 + xi4[n]];
        }
        fx += wwy[m] * sx;
        fy += wwy[m] * sy;
    }

    const float gx256 = -1.0f + 2.0f * (float)j / 255.0f;
    const float gy256 = -1.0f + 2.0f * (float)i / 255.0f;
    const float gx306 = -1.0f + 2.0f * (float)(j + 25) / 305.0f;
    const float gy306 = -1.0f + 2.0f * (float)(i + 25) / 305.0f;
    const float x = (fx - gx256 + gx306 + 1.0f) * 152.5f;
    const float y = (fy - gy256 + gy306 + 1.0f) * 152.5f;
    return make_float2(x, y);
}

// Full taps (fallback path only)
__device__ __forceinline__ bool pixel_taps(const float* __restrict__ flow, int b,
                                           int i, int j,
                                           float wx[4], float wy[4],
                                           int xs[4], int ys[4]) {
    const float2 xy = warp_coord(flow, b, i, j);
    const float x = xy.x, y = xy.y;
    const float ixf = floorf(x), iyf = floorf(y);
    const float tx = x - ixf, ty = y - iyf;
    wx[0] = cc2(tx + 1.f); wx[1] = cc1(tx); wx[2] = cc1(1.f - tx); wx[3] = cc2(2.f - tx);
    wy[0] = cc2(ty + 1.f); wy[1] = cc1(ty); wy[2] = cc1(1.f - ty); wy[3] = cc2(2.f - ty);
    const int ix = (int)ixf, iy = (int)iyf;

    bool anyx = false, anyy = false;
#pragma unroll
    for (int n = 0; n < 4; ++n) {
        int xx = ix - 1 + n;
        bool vx = (xx >= 0) && (xx < 306);
        anyx |= vx;
        if (!vx) wx[n] = 0.f;
        xs[n] = min(max(xx - 25, 0), 255);

        int yy = iy - 1 + n;
        bool vy = (yy >= 0) && (yy < 306);
        anyy |= vy;
        if (!vy) wy[n] = 0.f;
        ys[n] = min(max(yy - 25, 0), 255);
    }
    return anyx && anyy;
}

// ------- Kernel A: transpose + coordinate precompute ------------------------
// [B,C,H,W] fp32 -> ws [B,H*W,C] fp16 (67 MB read + 34 MB write, HBM-bound
// ~16 us) and, per thread (=1 pixel), the warped (x,y) into a float2 table
// (v10: flow interp hoisted here into idle VALU headroom).
__global__ __launch_bounds__(256) void transpose_clast_h_kernel(
    const float* __restrict__ inp, const float* __restrict__ flow,
    __half* __restrict__ ws, float2* __restrict__ coords)
{
    __shared__ float lds[32 * 260];
    const int blk = blockIdx.x;           // 2048
    const int b = blk & 7;                // XCD batch affinity
    const int p0 = (blk >> 3) << 8;       // 256-pixel tile
    const float* ib = inp + ((long)b << 21);
    const int tid = threadIdx.x;
    const int l = tid & 63;
    const int w = tid >> 6;

#pragma unroll
    for (int k = 0; k < 8; ++k) {
        const int c = (k << 2) + w;
        const float4 v = *(const float4*)(ib + ((long)c << 16) + p0 + (l << 2));
        *(float4*)&lds[c * 260 + (l << 2)] = v;
    }

    // coordinate precompute: independent of LDS, overlaps the barrier
    {
        const int pidx = p0 + tid;
        coords[((long)b << 16) + pidx] =
            warp_coord(flow, b, pidx >> 8, pidx & 255);
    }
    __syncthreads();

    // 16-B chunk f = q*256+tid of the block's 16-KB ws region:
    // pixel = f>>2, channel group = (f&3)*8 -> each wave-store 1 KB contiguous.
    __half* wsb = ws + (((long)b << 16) + p0) * 32;   // block base (fp16 elems)
#pragma unroll
    for (int q = 0; q < 4; ++q) {
        const int f  = (q << 8) + tid;
        const int px = f >> 2;
        const int c0 = (f & 3) << 3;
        __half2 h[4];
#pragma unroll
        for (int i = 0; i < 4; ++i) {
            float a  = lds[(c0 + 2 * i + 0) * 260 + px];
            float bb = lds[(c0 + 2 * i + 1) * 260 + px];
            h[i] = __float22half2_rn(make_float2(a, bb));
        }
        *(float4*)(wsb + ((long)f << 3)) = *(float4*)h;
    }
}

// ------- Kernel B: gather fp16 taps, 64 px/block ---------------------------
// v7 (kept): quad-adjacent load mapping (g=lane&3) -> 64-B line coalescing.
// v9 (kept): v_fma_mix_f32 inner loop. v10 (kept): precomputed coords.
// v11: drop the p_lds store re-stage. The quad-layout store is already
//      byte-coalesced (per instr: 4 channel planes x 16 consecutive px =
//      4 full 64-B segments). p_lds only cost: 8.3 KB LDS + a barrier.
//      LDS 16.9 -> 8.4 KB lifts the ~4-blocks/CU cap (v8 occupancy 48%,
//      the inferred real limiter after VALU cuts v9/v10 bought ~nothing)
//      to ~8 blocks/CU -> 2x waves hiding tap-load latency.
__global__ __launch_bounds__(256, 4) void gather_clast_h_kernel(
    const __half* __restrict__ ws,       // [B, 65536, 32] fp16
    const float2* __restrict__ coords,   // [B, 65536] warped (x,y)
    float* __restrict__ out)             // [B, 32, 256, 256] fp32
{
    __shared__ float w_lds[16][64];
    __shared__ int   o_lds[16][64];
    __shared__ int   v_lds[64];

    const int tid = threadIdx.x;
    const int blk = blockIdx.x;      // 8192
    const int b = blk & 7;           // XCD batch affinity
    const int pidx0 = (blk >> 3) << 6;   // 64 pixels per block

    // ---- m-split prologue: all 256 threads, no flow interp ----
    {
        const int px = tid & 63;
        const int m  = tid >> 6;
        const int pidx = pidx0 + px;

        const float2 xy = coords[((long)b << 16) + pidx];
        const float x = xy.x, y = xy.y;

        const float ixf = floorf(x), iyf = floorf(y);
        const float tx = x - ixf, ty = y - iyf;
        float wx[4], wy4[4];
        wx[0] = cc2(tx + 1.f); wx[1] = cc1(tx);
        wx[2] = cc1(1.f - tx); wx[3] = cc2(2.f - tx);
        wy4[0] = cc2(ty + 1.f); wy4[1] = cc1(ty);
        wy4[2] = cc1(1.f - ty); wy4[3] = cc2(2.f - ty);
        const int ix = (int)ixf, iy = (int)iyf;

        bool anyx = false, anyy = false;
        int xs4[4];
#pragma unroll
        for (int n = 0; n < 4; ++n) {
            int xx = ix - 1 + n;
            bool vx = (xx >= 0) && (xx < 306);
            anyx |= vx;
            if (!vx) wx[n] = 0.f;
            xs4[n] = min(max(xx - 25, 0), 255);

            int yy = iy - 1 + n;
            anyy |= (yy >= 0) && (yy < 306);
        }
        // row m only
        const int yym = iy - 1 + m;
        const bool vym = (yym >= 0) && (yym < 306);
        const float wym = vym ? wy4[m] : 0.f;
        const int ysm = min(max(yym - 25, 0), 255);
#pragma unroll
        for (int n = 0; n < 4; ++n) {
            w_lds[m * 4 + n][px] = wym * wx[n];
            o_lds[m * 4 + n][px] = (ysm << 13) + (xs4[n] << 5);
        }
        if (m == 0) v_lds[px] = (anyx && anyy) ? 1 : 0;
    }
    __syncthreads();

    const int lane = tid & 63;
    const int wv   = tid >> 6;               // wave 0..3
    const int g    = lane & 3;               // channel group: quad-adjacent!
    const int pl   = (wv << 4) + (lane >> 2); // local pixel 0..63

    const __half* baseh = ws + ((long)b << 21) + (g << 3);

    float acc[8];
#pragma unroll
    for (int k = 0; k < 8; ++k) acc[k] = 0.f;

    if (v_lds[pl]) {
#pragma unroll
        for (int k = 0; k < 16; ++k) {
            uint4 v = *(const uint4*)(baseh + o_lds[k][pl]);  // 8 fp16 ch
            const float w = w_lds[k][pl];
#pragma unroll
            for (int q = 0; q < 4; ++q) {
                const unsigned hv = (&v.x)[q];
                asm("v_fma_mix_f32 %0, %1, %2, %0 op_sel:[0,0,0] op_sel_hi:[1,0,0]"
                    : "+v"(acc[2 * q + 0]) : "v"(hv), "v"(w));
                asm("v_fma_mix_f32 %0, %1, %2, %0 op_sel:[1,0,0] op_sel_hi:[1,0,0]"
                    : "+v"(acc[2 * q + 1]) : "v"(hv), "v"(w));
            }
        }
    }

    // direct store in quad layout: per instruction the wave covers 4 channel
    // planes x 16 consecutive pixels = 4 contiguous 64-B segments (coalesced)
    const int pidx = pidx0 + pl;
    float* op = out + ((long)b << 21) + ((long)(g << 3) << 16) + pidx;
#pragma unroll
    for (int k = 0; k < 8; ++k)
        op[(long)k << 16] = acc[k];
}

// ---------------- Fallback if ws too small ----------------
__global__ __launch_bounds__(256) void warp_bicubic_fallback(
    const float* __restrict__ inp,
    const float* __restrict__ flow,
    float* __restrict__ out)
{
    const int j = threadIdx.x;
    const int i = blockIdx.x & 255;
    const int b = blockIdx.x >> 8;

    float wx[4], wy[4];
    int xs[4], ys[4];
    pixel_taps(flow, b, i, j, wx, wy, xs, ys);

    float* op = out + (long)b * 32 * 65536 + i * 256 + j;
    const float* ib = inp + (long)b * 32 * 65536;
#pragma unroll 2
    for (int c = 0; c < 32; ++c) {
        const float* s = ib + c * 65536;
        float acc = 0.f;
#pragma unroll
        for (int m = 0; m < 4; ++m) {
            float wm = wy[m];
            if (wm != 0.f) {
                const float* r = s + ys[m] * 256;
                acc += wm * (wx[0] * r[xs[0]] + wx[1] * r[xs[1]] +
                             wx[2] * r[xs[2]] + wx[3] * r[xs[3]]);
            }
        }
        op[c * 65536] = acc;
    }
}

extern "C" void kernel_launch(void* const* d_in, const int* in_sizes, int n_in,
                              void* d_out, int out_size, void* d_ws, size_t ws_size,
                              hipStream_t stream) {
    const float* inp  = (const float*)d_in[0];   // [8,32,256,256]
    const float* flow = (const float*)d_in[1];   // [8,2,64,64]
    float* out = (float*)d_out;

    const size_t half_bytes = (size_t)8 * 65536 * 32 * sizeof(__half);  // 32 MiB
    const size_t coord_bytes = (size_t)8 * 65536 * sizeof(float2);      // 4 MiB
    if (ws_size >= half_bytes + coord_bytes) {
        __half* ws = (__half*)d_ws;
        float2* coords = (float2*)((char*)d_ws + half_bytes);
        transpose_clast_h_kernel<<<dim3(2048), dim3(256), 0, stream>>>(inp, flow, ws, coords);
        gather_clast_h_kernel<<<dim3(8192), dim3(256), 0, stream>>>(ws, coords, out);
    } else {
        warp_bicubic_fallback<<<dim3(8 * 256), dim3(256), 0, stream>>>(inp, flow, out);
    }
}

// Round 12
// 142.416 us; speedup vs baseline: 1.0109x; 1.0109x over previous
//
#include <hip/hip_runtime.h>
#include <hip/hip_fp16.h>

// ---------------- bicubic helpers (A = -0.75, torch) ----------------
__device__ __forceinline__ float cc1(float x) {
    return (1.25f * x - 2.25f) * x * x + 1.0f;
}
__device__ __forceinline__ float cc2(float x) {
    return ((-0.75f * x + 3.75f) * x - 6.0f) * x + 3.0f;
}

__device__ __forceinline__ void axis64(int o, float w[4], int idx[4]) {
    float src = (float)o * 63.0f / 255.0f;
    float f = floorf(src);
    float t = src - f;
    w[0] = cc2(t + 1.0f);
    w[1] = cc1(t);
    w[2] = cc1(1.0f - t);
    w[3] = cc2(2.0f - t);
    int i0 = (int)f;
#pragma unroll
    for (int k = 0; k < 4; ++k) idx[k] = min(max(i0 - 1 + k, 0), 63);
}

// Warped absolute sample coordinate (x,y) in the padded [0,306) domain for
// output pixel (i,j), batch b. Pure per-pixel function of flow.
__device__ __forceinline__ float2 warp_coord(const float* __restrict__ flow,
                                             int b, int i, int j) {
    float wwy[4], wwx[4];
    int yi4[4], xi4[4];
    axis64(i, wwy, yi4);
    axis64(j, wwx, xi4);

    const float* fb = flow + (long)b * 2 * 4096;
    float fx = 0.f, fy = 0.f;
#pragma unroll
    for (int m = 0; m < 4; ++m) {
        const float* r0 = fb + yi4[m] * 64;
        float sx = 0.f, sy = 0.f;
#pragma unroll
        for (int n = 0; n < 4; ++n) {
            sx += wwx[n] * r0[xi4[n]];
            sy += wwx[n] * r0[4096 + xi4[n]];
        }
        fx += wwy[m] * sx;
        fy += wwy[m] * sy;
    }

    const float gx256 = -1.0f + 2.0f * (float)j / 255.0f;
    const float gy256 = -1.0f + 2.0f * (float)i / 255.0f;
    const float gx306 = -1.0f + 2.0f * (float)(j + 25) / 305.0f;
    const float gy306 = -1.0f + 2.0f * (float)(i + 25) / 305.0f;
    const float x = (fx - gx256 + gx306 + 1.0f) * 152.5f;
    const float y = (fy - gy256 + gy306 + 1.0f) * 152.5f;
    return make_float2(x, y);
}

// Full taps (fallback path only)
__device__ __forceinline__ bool pixel_taps(const float* __restrict__ flow, int b,
                                           int i, int j,
                                           float wx[4], float wy[4],
                                           int xs[4], int ys[4]) {
    const float2 xy = warp_coord(flow, b, i, j);
    const float x = xy.x, y = xy.y;
    const float ixf = floorf(x), iyf = floorf(y);
    const float tx = x - ixf, ty = y - iyf;
    wx[0] = cc2(tx + 1.f); wx[1] = cc1(tx); wx[2] = cc1(1.f - tx); wx[3] = cc2(2.f - tx);
    wy[0] = cc2(ty + 1.f); wy[1] = cc1(ty); wy[2] = cc1(1.f - ty); wy[3] = cc2(2.f - ty);
    const int ix = (int)ixf, iy = (int)iyf;

    bool anyx = false, anyy = false;
#pragma unroll
    for (int n = 0; n < 4; ++n) {
        int xx = ix - 1 + n;
        bool vx = (xx >= 0) && (xx < 306);
        anyx |= vx;
        if (!vx) wx[n] = 0.f;
        xs[n] = min(max(xx - 25, 0), 255);

        int yy = iy - 1 + n;
        bool vy = (yy >= 0) && (yy < 306);
        anyy |= vy;
        if (!vy) wy[n] = 0.f;
        ys[n] = min(max(yy - 25, 0), 255);
    }
    return anyx && anyy;
}

// ------- Kernel A: transpose + coordinate precompute ------------------------
// [B,C,H,W] fp32 -> ws [B,H*W,C] fp16 (67 MB read + 34 MB write, HBM-bound
// ~16 us) and, per thread (=1 pixel), the warped (x,y) into a float2 table
// (v10: flow interp hoisted here into idle VALU headroom).
__global__ __launch_bounds__(256) void transpose_clast_h_kernel(
    const float* __restrict__ inp, const float* __restrict__ flow,
    __half* __restrict__ ws, float2* __restrict__ coords)
{
    __shared__ float lds[32 * 260];
    const int blk = blockIdx.x;           // 2048
    const int b = blk & 7;                // XCD batch affinity
    const int p0 = (blk >> 3) << 8;       // 256-pixel tile
    const float* ib = inp + ((long)b << 21);
    const int tid = threadIdx.x;
    const int l = tid & 63;
    const int w = tid >> 6;

#pragma unroll
    for (int k = 0; k < 8; ++k) {
        const int c = (k << 2) + w;
        const float4 v = *(const float4*)(ib + ((long)c << 16) + p0 + (l << 2));
        *(float4*)&lds[c * 260 + (l << 2)] = v;
    }

    // coordinate precompute: independent of LDS, overlaps the barrier
    {
        const int pidx = p0 + tid;
        coords[((long)b << 16) + pidx] =
            warp_coord(flow, b, pidx >> 8, pidx & 255);
    }
    __syncthreads();

    // 16-B chunk f = q*256+tid of the block's 16-KB ws region:
    // pixel = f>>2, channel group = (f&3)*8 -> each wave-store 1 KB contiguous.
    __half* wsb = ws + (((long)b << 16) + p0) * 32;   // block base (fp16 elems)
#pragma unroll
    for (int q = 0; q < 4; ++q) {
        const int f  = (q << 8) + tid;
        const int px = f >> 2;
        const int c0 = (f & 3) << 3;
        __half2 h[4];
#pragma unroll
        for (int i = 0; i < 4; ++i) {
            float a  = lds[(c0 + 2 * i + 0) * 260 + px];
            float bb = lds[(c0 + 2 * i + 1) * 260 + px];
            h[i] = __float22half2_rn(make_float2(a, bb));
        }
        *(float4*)(wsb + ((long)f << 3)) = *(float4*)h;
    }
}

// ------- Kernel B: gather fp16 taps, 64 px/block ---------------------------
// v7 (kept): quad-adjacent load mapping (g=lane&3) -> 64-B line coalescing.
// v9 (kept): v_fma_mix_f32 inner loop. v10 (kept): precomputed coords +
//     p_lds store re-stage (v11 showed the direct quad store regresses:
//     4x64-B segments/instr vs staged 2x128-B).
// v12: overlay p_lds onto w_lds/o_lds via union. w/o are dead after the tap
//     loop; p is born after it (one extra barrier separates lifetimes).
//     LDS 16.9 -> ~8.6 KB: blocks/CU limit goes ~4 -> 8 (thread-cap), 2x
//     waves hiding tap-load latency, while keeping v10's coalesced stores.
__global__ __launch_bounds__(256, 4) void gather_clast_h_kernel(
    const __half* __restrict__ ws,       // [B, 65536, 32] fp16
    const float2* __restrict__ coords,   // [B, 65536] warped (x,y)
    float* __restrict__ out)             // [B, 32, 256, 256] fp32
{
    __shared__ union {
        struct {
            float w[16][64];     // [tap k][px] weights
            int   o[16][64];     // [tap k][px] offsets
        } in;                    // 8.2 KB, live: prologue + tap loop
        float p[4][8][65];       // [g][ch][px] staged results, 8.3 KB,
                                 // live: after tap loop
    } u;
    __shared__ int v_lds[64];

    const int tid = threadIdx.x;
    const int blk = blockIdx.x;      // 8192
    const int b = blk & 7;           // XCD batch affinity
    const int pidx0 = (blk >> 3) << 6;   // 64 pixels per block

    // ---- m-split prologue: all 256 threads, no flow interp ----
    {
        const int px = tid & 63;
        const int m  = tid >> 6;
        const int pidx = pidx0 + px;

        const float2 xy = coords[((long)b << 16) + pidx];
        const float x = xy.x, y = xy.y;

        const float ixf = floorf(x), iyf = floorf(y);
        const float tx = x - ixf, ty = y - iyf;
        float wx[4], wy4[4];
        wx[0] = cc2(tx + 1.f); wx[1] = cc1(tx);
        wx[2] = cc1(1.f - tx); wx[3] = cc2(2.f - tx);
        wy4[0] = cc2(ty + 1.f); wy4[1] = cc1(ty);
        wy4[2] = cc1(1.f - ty); wy4[3] = cc2(2.f - ty);
        const int ix = (int)ixf, iy = (int)iyf;

        bool anyx = false, anyy = false;
        int xs4[4];
#pragma unroll
        for (int n = 0; n < 4; ++n) {
            int xx = ix - 1 + n;
            bool vx = (xx >= 0) && (xx < 306);
            anyx |= vx;
            if (!vx) wx[n] = 0.f;
            xs4[n] = min(max(xx - 25, 0), 255);

            int yy = iy - 1 + n;
            anyy |= (yy >= 0) && (yy < 306);
        }
        // row m only
        const int yym = iy - 1 + m;
        const bool vym = (yym >= 0) && (yym < 306);
        const float wym = vym ? wy4[m] : 0.f;
        const int ysm = min(max(yym - 25, 0), 255);
#pragma unroll
        for (int n = 0; n < 4; ++n) {
            u.in.w[m * 4 + n][px] = wym * wx[n];
            u.in.o[m * 4 + n][px] = (ysm << 13) + (xs4[n] << 5);
        }
        if (m == 0) v_lds[px] = (anyx && anyy) ? 1 : 0;
    }
    __syncthreads();

    const int lane = tid & 63;
    const int wv   = tid >> 6;               // wave 0..3
    const int g    = lane & 3;               // channel group: quad-adjacent!
    const int pl   = (wv << 4) + (lane >> 2); // local pixel 0..63

    const __half* baseh = ws + ((long)b << 21) + (g << 3);

    float acc[8];
#pragma unroll
    for (int k = 0; k < 8; ++k) acc[k] = 0.f;

    if (v_lds[pl]) {
#pragma unroll
        for (int k = 0; k < 16; ++k) {
            uint4 v = *(const uint4*)(baseh + u.in.o[k][pl]);  // 8 fp16 ch
            const float w = u.in.w[k][pl];
#pragma unroll
            for (int q = 0; q < 4; ++q) {
                const unsigned hv = (&v.x)[q];
                asm("v_fma_mix_f32 %0, %1, %2, %0 op_sel:[0,0,0] op_sel_hi:[1,0,0]"
                    : "+v"(acc[2 * q + 0]) : "v"(hv), "v"(w));
                asm("v_fma_mix_f32 %0, %1, %2, %0 op_sel:[1,0,0] op_sel_hi:[1,0,0]"
                    : "+v"(acc[2 * q + 1]) : "v"(hv), "v"(w));
            }
        }
    }
    __syncthreads();   // w/o lifetime ends; p lifetime begins

    // stage through LDS so global stores keep the v2 coalesced mapping
#pragma unroll
    for (int k = 0; k < 8; ++k) u.p[g][k][pl] = acc[k];
    __syncthreads();

    const int g2  = lane >> 4;                // store mapping (v2): adjacent
    const int pl2 = (wv << 4) + (lane & 15);  // lanes = consecutive pixels
    const int pidx = pidx0 + pl2;
    float* op = out + ((long)b << 21) + ((long)(g2 << 3) << 16) + pidx;
#pragma unroll
    for (int k = 0; k < 8; ++k)
        op[(long)k << 16] = u.p[g2][k][pl2];
}

// ---------------- Fallback if ws too small ----------------
__global__ __launch_bounds__(256) void warp_bicubic_fallback(
    const float* __restrict__ inp,
    const float* __restrict__ flow,
    float* __restrict__ out)
{
    const int j = threadIdx.x;
    const int i = blockIdx.x & 255;
    const int b = blockIdx.x >> 8;

    float wx[4], wy[4];
    int xs[4], ys[4];
    pixel_taps(flow, b, i, j, wx, wy, xs, ys);

    float* op = out + (long)b * 32 * 65536 + i * 256 + j;
    const float* ib = inp + (long)b * 32 * 65536;
#pragma unroll 2
    for (int c = 0; c < 32; ++c) {
        const float* s = ib + c * 65536;
        float acc = 0.f;
#pragma unroll
        for (int m = 0; m < 4; ++m) {
            float wm = wy[m];
            if (wm != 0.f) {
                const float* r = s + ys[m] * 256;
                acc += wm * (wx[0] * r[xs[0]] + wx[1] * r[xs[1]] +
                             wx[2] * r[xs[2]] + wx[3] * r[xs[3]]);
            }
        }
        op[c * 65536] = acc;
    }
}

extern "C" void kernel_launch(void* const* d_in, const int* in_sizes, int n_in,
                              void* d_out, int out_size, void* d_ws, size_t ws_size,
                              hipStream_t stream) {
    const float* inp  = (const float*)d_in[0];   // [8,32,256,256]
    const float* flow = (const float*)d_in[1];   // [8,2,64,64]
    float* out = (float*)d_out;

    const size_t half_bytes = (size_t)8 * 65536 * 32 * sizeof(__half);  // 32 MiB
    const size_t coord_bytes = (size_t)8 * 65536 * sizeof(float2);      // 4 MiB
    if (ws_size >= half_bytes + coord_bytes) {
        __half* ws = (__half*)d_ws;
        float2* coords = (float2*)((char*)d_ws + half_bytes);
        transpose_clast_h_kernel<<<dim3(2048), dim3(256), 0, stream>>>(inp, flow, ws, coords);
        gather_clast_h_kernel<<<dim3(8192), dim3(256), 0, stream>>>(ws, coords, out);
    } else {
        warp_bicubic_fallback<<<dim3(8 * 256), dim3(256), 0, stream>>>(inp, flow, out);
    }
}

// Round 13
// 140.582 us; speedup vs baseline: 1.0241x; 1.0130x over previous
//
#include <hip/hip_runtime.h>
#include <hip/hip_fp16.h>

// ---------------- bicubic helpers (A = -0.75, torch) ----------------
__device__ __forceinline__ float cc1(float x) {
    return (1.25f * x - 2.25f) * x * x + 1.0f;
}
__device__ __forceinline__ float cc2(float x) {
    return ((-0.75f * x + 3.75f) * x - 6.0f) * x + 3.0f;
}

__device__ __forceinline__ void axis64(int o, float w[4], int idx[4]) {
    float src = (float)o * 63.0f / 255.0f;
    float f = floorf(src);
    float t = src - f;
    w[0] = cc2(t + 1.0f);
    w[1] = cc1(t);
    w[2] = cc1(1.0f - t);
    w[3] = cc2(2.0f - t);
    int i0 = (int)f;
#pragma unroll
    for (int k = 0; k < 4; ++k) idx[k] = min(max(i0 - 1 + k, 0), 63);
}

// Warped absolute sample coordinate (x,y) in the padded [0,306) domain for
// output pixel (i,j), batch b. Pure per-pixel function of flow.
__device__ __forceinline__ float2 warp_coord(const float* __restrict__ flow,
                                             int b, int i, int j) {
    float wwy[4], wwx[4];
    int yi4[4], xi4[4];
    axis64(i, wwy, yi4);
    axis64(j, wwx, xi4);

    const float* fb = flow + (long)b * 2 * 4096;
    float fx = 0.f, fy = 0.f;
#pragma unroll
    for (int m = 0; m < 4; ++m) {
        const float* r0 = fb + yi4[m] * 64;
        float sx = 0.f, sy = 0.f;
#pragma unroll
        for (int n = 0; n < 4; ++n) {
            sx += wwx[n] * r0[xi4[n]];
            sy += wwx[n] * r0[4096 + xi4[n]];
        }
        fx += wwy[m] * sx;
        fy += wwy[m] * sy;
    }

    const float gx256 = -1.0f + 2.0f * (float)j / 255.0f;
    const float gy256 = -1.0f + 2.0f * (float)i / 255.0f;
    const float gx306 = -1.0f + 2.0f * (float)(j + 25) / 305.0f;
    const float gy306 = -1.0f + 2.0f * (float)(i + 25) / 305.0f;
    const float x = (fx - gx256 + gx306 + 1.0f) * 152.5f;
    const float y = (fy - gy256 + gy306 + 1.0f) * 152.5f;
    return make_float2(x, y);
}

// Full taps (fallback path only)
__device__ __forceinline__ bool pixel_taps(const float* __restrict__ flow, int b,
                                           int i, int j,
                                           float wx[4], float wy[4],
                                           int xs[4], int ys[4]) {
    const float2 xy = warp_coord(flow, b, i, j);
    const float x = xy.x, y = xy.y;
    const float ixf = floorf(x), iyf = floorf(y);
    const float tx = x - ixf, ty = y - iyf;
    wx[0] = cc2(tx + 1.f); wx[1] = cc1(tx); wx[2] = cc1(1.f - tx); wx[3] = cc2(2.f - tx);
    wy[0] = cc2(ty + 1.f); wy[1] = cc1(ty); wy[2] = cc1(1.f - ty); wy[3] = cc2(2.f - ty);
    const int ix = (int)ixf, iy = (int)iyf;

    bool anyx = false, anyy = false;
#pragma unroll
    for (int n = 0; n < 4; ++n) {
        int xx = ix - 1 + n;
        bool vx = (xx >= 0) && (xx < 306);
        anyx |= vx;
        if (!vx) wx[n] = 0.f;
        xs[n] = min(max(xx - 25, 0), 255);

        int yy = iy - 1 + n;
        bool vy = (yy >= 0) && (yy < 306);
        anyy |= vy;
        if (!vy) wy[n] = 0.f;
        ys[n] = min(max(yy - 25, 0), 255);
    }
    return anyx && anyy;
}

// ------- Kernel A: transpose + coordinate precompute ------------------------
// [B,C,H,W] fp32 -> ws [B,H*W,C] fp16 (67 MB read + 34 MB write, HBM-bound
// ~16 us) and, per thread (=1 pixel), the warped (x,y) into a float2 table
// (v10: flow interp hoisted here into idle VALU headroom).
__global__ __launch_bounds__(256) void transpose_clast_h_kernel(
    const float* __restrict__ inp, const float* __restrict__ flow,
    __half* __restrict__ ws, float2* __restrict__ coords)
{
    __shared__ float lds[32 * 260];
    const int blk = blockIdx.x;           // 2048
    const int b = blk & 7;                // XCD batch affinity
    const int p0 = (blk >> 3) << 8;       // 256-pixel tile
    const float* ib = inp + ((long)b << 21);
    const int tid = threadIdx.x;
    const int l = tid & 63;
    const int w = tid >> 6;

#pragma unroll
    for (int k = 0; k < 8; ++k) {
        const int c = (k << 2) + w;
        const float4 v = *(const float4*)(ib + ((long)c << 16) + p0 + (l << 2));
        *(float4*)&lds[c * 260 + (l << 2)] = v;
    }

    // coordinate precompute: independent of LDS, overlaps the barrier
    {
        const int pidx = p0 + tid;
        coords[((long)b << 16) + pidx] =
            warp_coord(flow, b, pidx >> 8, pidx & 255);
    }
    __syncthreads();

    // 16-B chunk f = q*256+tid of the block's 16-KB ws region:
    // pixel = f>>2, channel group = (f&3)*8 -> each wave-store 1 KB contiguous.
    __half* wsb = ws + (((long)b << 16) + p0) * 32;   // block base (fp16 elems)
#pragma unroll
    for (int q = 0; q < 4; ++q) {
        const int f  = (q << 8) + tid;
        const int px = f >> 2;
        const int c0 = (f & 3) << 3;
        __half2 h[4];
#pragma unroll
        for (int i = 0; i < 4; ++i) {
            float a  = lds[(c0 + 2 * i + 0) * 260 + px];
            float bb = lds[(c0 + 2 * i + 1) * 260 + px];
            h[i] = __float22half2_rn(make_float2(a, bb));
        }
        *(float4*)(wsb + ((long)f << 3)) = *(float4*)h;
    }
}

// ------- Kernel B: gather fp16 taps, 64 px/block ---------------------------
// v13 == v10 exactly (measured best: 140.9 us total). Kept levers:
//   v7: quad-adjacent load mapping (g=lane&3) -> 64-B line coalescing
//   v9: v_fma_mix_f32 inner loop (f16 source consumed by f32 FMA)
//   v10: precomputed coords; p_lds re-stage for 2x128-B coalesced stores
// Falsified levers (do not retry): per-lane MLP (v3/v4), wave-TLP tap-split
// (v6), direct quad store (v11), LDS union for occupancy (v12).
__global__ __launch_bounds__(256, 4) void gather_clast_h_kernel(
    const __half* __restrict__ ws,       // [B, 65536, 32] fp16
    const float2* __restrict__ coords,   // [B, 65536] warped (x,y)
    float* __restrict__ out)             // [B, 32, 256, 256] fp32
{
    __shared__ float w_lds[16][64];
    __shared__ int   o_lds[16][64];
    __shared__ int   v_lds[64];
    __shared__ float p_lds[4][8][65];    // [g][ch][px] staged results, 8.3 KB

    const int tid = threadIdx.x;
    const int blk = blockIdx.x;      // 8192
    const int b = blk & 7;           // XCD batch affinity
    const int pidx0 = (blk >> 3) << 6;   // 64 pixels per block

    // ---- m-split prologue: all 256 threads, no flow interp ----
    {
        const int px = tid & 63;
        const int m  = tid >> 6;
        const int pidx = pidx0 + px;

        const float2 xy = coords[((long)b << 16) + pidx];
        const float x = xy.x, y = xy.y;

        const float ixf = floorf(x), iyf = floorf(y);
        const float tx = x - ixf, ty = y - iyf;
        float wx[4], wy4[4];
        wx[0] = cc2(tx + 1.f); wx[1] = cc1(tx);
        wx[2] = cc1(1.f - tx); wx[3] = cc2(2.f - tx);
        wy4[0] = cc2(ty + 1.f); wy4[1] = cc1(ty);
        wy4[2] = cc1(1.f - ty); wy4[3] = cc2(2.f - ty);
        const int ix = (int)ixf, iy = (int)iyf;

        bool anyx = false, anyy = false;
        int xs4[4];
#pragma unroll
        for (int n = 0; n < 4; ++n) {
            int xx = ix - 1 + n;
            bool vx = (xx >= 0) && (xx < 306);
            anyx |= vx;
            if (!vx) wx[n] = 0.f;
            xs4[n] = min(max(xx - 25, 0), 255);

            int yy = iy - 1 + n;
            anyy |= (yy >= 0) && (yy < 306);
        }
        // row m only
        const int yym = iy - 1 + m;
        const bool vym = (yym >= 0) && (yym < 306);
        const float wym = vym ? wy4[m] : 0.f;
        const int ysm = min(max(yym - 25, 0), 255);
#pragma unroll
        for (int n = 0; n < 4; ++n) {
            w_lds[m * 4 + n][px] = wym * wx[n];
            o_lds[m * 4 + n][px] = (ysm << 13) + (xs4[n] << 5);
        }
        if (m == 0) v_lds[px] = (anyx && anyy) ? 1 : 0;
    }
    __syncthreads();

    const int lane = tid & 63;
    const int wv   = tid >> 6;               // wave 0..3
    const int g    = lane & 3;               // channel group: quad-adjacent!
    const int pl   = (wv << 4) + (lane >> 2); // local pixel 0..63

    const __half* baseh = ws + ((long)b << 21) + (g << 3);

    float acc[8];
#pragma unroll
    for (int k = 0; k < 8; ++k) acc[k] = 0.f;

    if (v_lds[pl]) {
#pragma unroll
        for (int k = 0; k < 16; ++k) {
            uint4 v = *(const uint4*)(baseh + o_lds[k][pl]);  // 8 fp16 ch
            const float w = w_lds[k][pl];
#pragma unroll
            for (int q = 0; q < 4; ++q) {
                const unsigned hv = (&v.x)[q];
                asm("v_fma_mix_f32 %0, %1, %2, %0 op_sel:[0,0,0] op_sel_hi:[1,0,0]"
                    : "+v"(acc[2 * q + 0]) : "v"(hv), "v"(w));
                asm("v_fma_mix_f32 %0, %1, %2, %0 op_sel:[1,0,0] op_sel_hi:[1,0,0]"
                    : "+v"(acc[2 * q + 1]) : "v"(hv), "v"(w));
            }
        }
    }

    // stage through LDS so global stores keep the v2 coalesced mapping
#pragma unroll
    for (int k = 0; k < 8; ++k) p_lds[g][k][pl] = acc[k];
    __syncthreads();

    const int g2  = lane >> 4;                // store mapping (v2): adjacent
    const int pl2 = (wv << 4) + (lane & 15);  // lanes = consecutive pixels
    const int pidx = pidx0 + pl2;
    float* op = out + ((long)b << 21) + ((long)(g2 << 3) << 16) + pidx;
#pragma unroll
    for (int k = 0; k < 8; ++k)
        op[(long)k << 16] = p_lds[g2][k][pl2];
}

// ---------------- Fallback if ws too small ----------------
__global__ __launch_bounds__(256) void warp_bicubic_fallback(
    const float* __restrict__ inp,
    const float* __restrict__ flow,
    float* __restrict__ out)
{
    const int j = threadIdx.x;
    const int i = blockIdx.x & 255;
    const int b = blockIdx.x >> 8;

    float wx[4], wy[4];
    int xs[4], ys[4];
    pixel_taps(flow, b, i, j, wx, wy, xs, ys);

    float* op = out + (long)b * 32 * 65536 + i * 256 + j;
    const float* ib = inp + (long)b * 32 * 65536;
#pragma unroll 2
    for (int c = 0; c < 32; ++c) {
        const float* s = ib + c * 65536;
        float acc = 0.f;
#pragma unroll
        for (int m = 0; m < 4; ++m) {
            float wm = wy[m];
            if (wm != 0.f) {
                const float* r = s + ys[m] * 256;
                acc += wm * (wx[0] * r[xs[0]] + wx[1] * r[xs[1]] +
                             wx[2] * r[xs[2]] + wx[3] * r[xs[3]]);
            }
        }
        op[c * 65536] = acc;
    }
}

extern "C" void kernel_launch(void* const* d_in, const int* in_sizes, int n_in,
                              void* d_out, int out_size, void* d_ws, size_t ws_size,
                              hipStream_t stream) {
    const float* inp  = (const float*)d_in[0];   // [8,32,256,256]
    const float* flow = (const float*)d_in[1];   // [8,2,64,64]
    float* out = (float*)d_out;

    const size_t half_bytes = (size_t)8 * 65536 * 32 * sizeof(__half);  // 32 MiB
    const size_t coord_bytes = (size_t)8 * 65536 * sizeof(float2);      // 4 MiB
    if (ws_size >= half_bytes + coord_bytes) {
        __half* ws = (__half*)d_ws;
        float2* coords = (float2*)((char*)d_ws + half_bytes);
        transpose_clast_h_kernel<<<dim3(2048), dim3(256), 0, stream>>>(inp, flow, ws, coords);
        gather_clast_h_kernel<<<dim3(8192), dim3(256), 0, stream>>>(ws, coords, out);
    } else {
        warp_bicubic_fallback<<<dim3(8 * 256), dim3(256), 0, stream>>>(inp, flow, out);
    }
}